// Round 6
// baseline (106.418 us; speedup 1.0000x reference)
//
#include <hip/hip_runtime.h>

static constexpr int CH   = 128;   // CHANNELS
static constexpr int KW   = 160;   // W row length (bf16): 128 tok + wc0,wc1,b1 + pad
static constexpr int KPAD = 192;   // Atile row length (bf16) -> 384B rows

typedef __attribute__((ext_vector_type(8))) short bf16x8;
typedef __attribute__((ext_vector_type(4))) float f32x4;

__device__ inline unsigned short f2bf(float x) {
    unsigned int u = __float_as_uint(x);
    unsigned int r = (u + 0x7fffu + ((u >> 16) & 1u)) >> 16;  // RNE
    return (unsigned short)r;
}
__device__ inline unsigned int pack2bf(float a, float b) {
    return (unsigned int)f2bf(a) | ((unsigned int)f2bf(b) << 16);
}

// meta layout (u32): [0]=is64 flag, [1..64]=hist, [65..128]=cursor(base),
//                    [129..137]=rstart (region starts per src slice, +end)
// ---------------------------------------------------------------------------
__global__ void prep0(const unsigned int* __restrict__ idxw,
                      unsigned int* __restrict__ meta) {
    const int t = threadIdx.x;
    unsigned int nz = 0;
    for (int i = t; i < 128; i += 64) nz |= idxw[2 * i + 1];
    unsigned long long b = __ballot(nz != 0u);
    if (t == 0) meta[0] = (b == 0ULL) ? 1u : 0u;  // int64 detect
    if (t < 64) meta[1 + t] = 0u;                 // zero hist
}

// ---------------------------------------------------------------------------
// Histogram over 64 buckets: bucket = slice(src)*8 + slice(dst),
// slice(n) = umulhi(n, M32)  (M32 = ceil(2^32 / slice_size)).
// ---------------------------------------------------------------------------
__global__ __launch_bounds__(256) void hist_kern(
    const unsigned int* __restrict__ idxw, int E, unsigned int M32,
    unsigned int* __restrict__ meta) {
    __shared__ unsigned int lh[64];
    const int t = threadIdx.x;
    if (t < 64) lh[t] = 0;
    __syncthreads();
    const int is64 = meta[0];
    const int stride = gridDim.x * blockDim.x;
    for (int e = blockIdx.x * blockDim.x + t; e < E; e += stride) {
        const unsigned s = is64 ? idxw[2 * e] : idxw[e];
        const unsigned d = is64 ? idxw[2 * (E + e)] : idxw[E + e];
        const unsigned b = __umulhi(s, M32) * 8u + __umulhi(d, M32);
        atomicAdd(&lh[b], 1u);
    }
    __syncthreads();
    if (t < 64 && lh[t]) atomicAdd(&meta[1 + t], lh[t]);
}

__global__ void scan_kern(unsigned int* __restrict__ meta, int E) {
    if (threadIdx.x == 0) {
        unsigned int acc = 0;
        for (int b = 0; b < 64; ++b) {
            if ((b & 7) == 0) meta[129 + (b >> 3)] = acc;  // region start
            meta[65 + b] = acc;                            // cursor = base
            acc += meta[1 + b];
        }
        meta[137] = (unsigned int)E;
    }
}

// ---------------------------------------------------------------------------
// Scatter into sorted[]: entry = { src | (dst<<16), edge_id }. Two-phase
// per-chunk: LDS rank -> one global atomic per bucket per block -> write.
// ---------------------------------------------------------------------------
__global__ __launch_bounds__(256) void scatter_kern(
    const unsigned int* __restrict__ idxw, int E, unsigned int M32,
    unsigned int* __restrict__ meta, uint2* __restrict__ sorted) {
    __shared__ unsigned int lh[64], gb[64];
    const int t = threadIdx.x;
    const int is64 = meta[0];
    const int cstride = gridDim.x * 1024;
    for (int cb = blockIdx.x * 1024; cb < E; cb += cstride) {
        if (t < 64) lh[t] = 0;
        __syncthreads();
        unsigned sv[4], dv[4], bb[4], rk[4];
        bool ok[4];
#pragma unroll
        for (int j = 0; j < 4; ++j) {
            const int e = cb + j * 256 + t;
            ok[j] = e < E;
            if (ok[j]) {
                sv[j] = is64 ? idxw[2 * e] : idxw[e];
                dv[j] = is64 ? idxw[2 * (E + e)] : idxw[E + e];
                bb[j] = __umulhi(sv[j], M32) * 8u + __umulhi(dv[j], M32);
                rk[j] = atomicAdd(&lh[bb[j]], 1u);
            }
        }
        __syncthreads();
        if (t < 64) gb[t] = lh[t] ? atomicAdd(&meta[65 + t], lh[t]) : 0u;
        __syncthreads();
#pragma unroll
        for (int j = 0; j < 4; ++j) {
            if (ok[j]) {
                const int e = cb + j * 256 + t;
                sorted[gb[bb[j]] + rk[j]] =
                    make_uint2(sv[j] | (dv[j] << 16), (unsigned)e);
            }
        }
        __syncthreads();  // all done with gb/lh before next iteration re-zeros
    }
}

// ---------------------------------------------------------------------------
// W[c][k] (bf16, [256][KW]): k<128 tok-weights; k=128/129 = +-wc0/wc1;
// k=130 = b1 (Q only); rest 0.
// ---------------------------------------------------------------------------
__global__ __launch_bounds__(192) void w1_prep(const float* __restrict__ w1,
                                               const float* __restrict__ b1,
                                               unsigned short* __restrict__ W) {
    const int c = blockIdx.x;    // 0..255
    const int k = threadIdx.x;
    if (k >= KW) return;
    const bool isQ = c >= 128;
    const int cc = c & 127;
    float v;
    if (k < 128)       v = isQ ? w1[(size_t)(128 + k) * CH + cc]
                               : w1[(size_t)k * CH + cc];
    else if (k == 128) v = (isQ ? 1.f : -1.f) * w1[(size_t)(2 * CH) * CH + cc];
    else if (k == 129) v = (isQ ? 1.f : -1.f) * w1[(size_t)(2 * CH + 1) * CH + cc];
    else if (k == 130) v = isQ ? b1[cc] : 0.f;
    else               v = 0.f;
    W[(size_t)c * KW + k] = f2bf(v);
}

// ---------------------------------------------------------------------------
// Node stage: 32 nodes x 256 cols per block (more waves/CU than 64-node tile).
// Swapped operands (A = W rows = output cols) -> packed 8B stores, no epilogue.
// ---------------------------------------------------------------------------
__global__ __launch_bounds__(256) void node_mfma3(
    const float* __restrict__ tokens, const float* __restrict__ coords,
    const unsigned short* __restrict__ W, unsigned short* __restrict__ Pb,
    unsigned short* __restrict__ Qb, int N) {
    __shared__ unsigned short Atile[32 * KPAD];  // 12 KB, XOR-swizzled rows

    const int t    = threadIdx.x;
    const int l    = t & 63;
    const int wid  = t >> 6;
    const int n0   = blockIdx.x * 32;
    const int woff = wid * 64;
    const int bl   = l & 15;
    const int bh   = l >> 4;

    // token chunks: 32 nodes x 16 chunks of 16B
#pragma unroll
    for (int it = 0; it < 2; ++it) {
        const int idx  = it * 256 + t;
        const int node = idx >> 4;
        const int cq   = idx & 15;
        float4 v0 = make_float4(0.f, 0.f, 0.f, 0.f);
        float4 v1 = v0;
        if (n0 + node < N) {
            const float* src = &tokens[(size_t)(n0 + node) * CH + cq * 8];
            v0 = *(const float4*)src;
            v1 = *(const float4*)(src + 4);
        }
        uint4 u;
        u.x = pack2bf(v0.x, v0.y);
        u.y = pack2bf(v0.z, v0.w);
        u.z = pack2bf(v1.x, v1.y);
        u.w = pack2bf(v1.z, v1.w);
        const int byte = node * 384 + ((cq * 16) ^ ((node & 7) << 4));
        *(uint4*)((char*)Atile + byte) = u;
    }
    // ext chunks: k=128..191 -> (cx, cy, 1, 0, ...)
    {
        const int node = t >> 3;
        const int ce   = t & 7;
        uint4 u = make_uint4(0u, 0u, 0u, 0u);
        if (ce == 0 && n0 + node < N) {
            const float cx = coords[2 * (n0 + node)];
            const float cy = coords[2 * (n0 + node) + 1];
            u.x = pack2bf(cx, cy);
            u.y = pack2bf(1.f, 0.f);
        }
        const int byte = node * 384 + (((16 + ce) * 16) ^ ((node & 7) << 4));
        *(uint4*)((char*)Atile + byte) = u;
    }
    __syncthreads();

    f32x4 acc[4][2];
#pragma unroll
    for (int m = 0; m < 4; ++m)
#pragma unroll
        for (int n = 0; n < 2; ++n) acc[m][n] = (f32x4){0.f, 0.f, 0.f, 0.f};

#pragma unroll
    for (int ks = 0; ks < 5; ++ks) {
        bf16x8 wfrag[4], tfrag[2];
#pragma unroll
        for (int m = 0; m < 4; ++m)
            wfrag[m] = *(const bf16x8*)&W[(size_t)(woff + m * 16 + bl) * KW +
                                          ks * 32 + bh * 8];
#pragma unroll
        for (int n = 0; n < 2; ++n) {
            const int row  = n * 16 + bl;
            const int byte = row * 384 + ((ks * 64 + bh * 16) ^ ((row & 7) << 4));
            tfrag[n] = *(const bf16x8*)((const char*)Atile + byte);
        }
#pragma unroll
        for (int m = 0; m < 4; ++m)
#pragma unroll
            for (int n = 0; n < 2; ++n)
                acc[m][n] = __builtin_amdgcn_mfma_f32_16x16x32_bf16(
                    wfrag[m], tfrag[n], acc[m][n], 0, 0, 0);
    }

#pragma unroll
    for (int m = 0; m < 4; ++m) {
        const int c = woff + m * 16 + bh * 4;
        unsigned short* dst = (c < CH) ? Pb : Qb;
        const int cc = c & (CH - 1);
#pragma unroll
        for (int n = 0; n < 2; ++n) {
            const int node = n0 + n * 16 + bl;
            if (node < N) {
                uint2 val;
                val.x = pack2bf(acc[m][n][0], acc[m][n][1]);
                val.y = pack2bf(acc[m][n][2], acc[m][n][3]);
                *(uint2*)&dst[(size_t)node * CH + cc] = val;
            }
        }
    }
}

// ---------------------------------------------------------------------------
// Sorted edge kernel: blocks with blockIdx%8 == x process src-slice region x
// (contiguous after sort; XCD round-robin heuristic pins the P/Q slices in
// that XCD's L2). 16-lane group owns 4 edges; lane covers 8 channels (16B).
// ---------------------------------------------------------------------------
__global__ __launch_bounds__(256) void edge_sorted(
    const uint2* __restrict__ sorted, const unsigned int* __restrict__ meta,
    const char* __restrict__ Pb, const char* __restrict__ Qb,
    const float* __restrict__ w2, const float* __restrict__ b2,
    float* __restrict__ out) {
    const int t  = threadIdx.x;
    const int gl = t & 15;
    const int g  = t >> 4;   // group 0..15, 4 edges each -> 64 edges/block/chunk
    const int x     = blockIdx.x & 7;
    const int bin   = blockIdx.x >> 3;
    const int nbins = gridDim.x >> 3;
    const unsigned r0 = meta[129 + x];
    const unsigned r1 = meta[129 + x + 1];
    if (r1 <= r0) return;
    const unsigned nch = (r1 - r0 + 63) >> 6;
    const float4 w2a = *(const float4*)&w2[8 * gl];
    const float4 w2b = *(const float4*)&w2[8 * gl + 4];
    const float bias = b2[0];

    for (unsigned c = bin; c < nch; c += nbins) {
        const unsigned be = r0 + c * 64 + g * 4;
        const unsigned me = be + (gl & 3);
        const uint2 ent = sorted[me < r1 ? me : r1 - 1];

        // broadcast the 4 packed node-pairs, issue all 8 gathers first
        unsigned soff[4], doff[4];
#pragma unroll
        for (int j = 0; j < 4; ++j) {
            const unsigned sx = __shfl(ent.x, j, 16);
            soff[j] = (sx & 0xffffu) << 8;
            doff[j] = (sx >> 16) << 8;
        }
        uint4 pv[4], qv[4];
#pragma unroll
        for (int j = 0; j < 4; ++j)
            pv[j] = *(const uint4*)(Pb + soff[j] + 16 * gl);
#pragma unroll
        for (int j = 0; j < 4; ++j)
            qv[j] = *(const uint4*)(Qb + doff[j] + 16 * gl);

        float part[4];
#pragma unroll
        for (int j = 0; j < 4; ++j) {
            float acc = 0.f;
            const unsigned pw[4] = {pv[j].x, pv[j].y, pv[j].z, pv[j].w};
            const unsigned qw[4] = {qv[j].x, qv[j].y, qv[j].z, qv[j].w};
            const float wv[8] = {w2a.x, w2a.y, w2a.z, w2a.w,
                                 w2b.x, w2b.y, w2b.z, w2b.w};
#pragma unroll
            for (int wdx = 0; wdx < 4; ++wdx) {
                const float plo = __uint_as_float(pw[wdx] << 16);
                const float phi = __uint_as_float(pw[wdx] & 0xffff0000u);
                const float qlo = __uint_as_float(qw[wdx] << 16);
                const float qhi = __uint_as_float(qw[wdx] & 0xffff0000u);
                const float hlo = fmaxf(plo + qlo, 0.f);
                const float hhi = fmaxf(phi + qhi, 0.f);
                acc = fmaf(hlo, wv[2 * wdx], acc);
                acc = fmaf(hhi, wv[2 * wdx + 1], acc);
            }
            part[j] = acc;
        }

        // width-16 butterfly with packing; lane (gl&3)=j ends with edge j's sum
        float t0 = part[0] + __shfl_xor(part[0], 1);
        float t1 = part[1] + __shfl_xor(part[1], 1);
        float t2 = part[2] + __shfl_xor(part[2], 1);
        float t3 = part[3] + __shfl_xor(part[3], 1);
        float a0 = (gl & 1) ? t1 : t0;
        float a1 = (gl & 1) ? t3 : t2;
        a0 += __shfl_xor(a0, 2);
        a1 += __shfl_xor(a1, 2);
        float cv = (gl & 2) ? a1 : a0;
        cv += __shfl_xor(cv, 4);
        cv += __shfl_xor(cv, 8);

        // lane gl<4 holds edge be+gl's sum; its own ent.y is that edge's id
        if (gl < 4 && be + gl < r1) out[ent.y] = cv + bias;
    }
}

extern "C" void kernel_launch(void* const* d_in, const int* in_sizes, int n_in,
                              void* d_out, int out_size, void* d_ws,
                              size_t ws_size, hipStream_t stream) {
    const float* tokens = (const float*)d_in[0];
    const float* coords = (const float*)d_in[1];
    const unsigned int* idxw = (const unsigned int*)d_in[2];
    const float* w1 = (const float*)d_in[3];
    const float* b1 = (const float*)d_in[4];
    const float* w2 = (const float*)d_in[5];
    const float* b2 = (const float*)d_in[6];
    float* out = (float*)d_out;

    const int N = in_sizes[0] / CH;       // 50000
    const int E = in_sizes[2] / 2;        // 800000
    const unsigned d_slice = (unsigned)((N + 7) / 8);
    const unsigned M32 = (unsigned)((0x100000000ULL + d_slice - 1) / d_slice);

    unsigned short* Pb = (unsigned short*)d_ws;
    unsigned short* Qb = Pb + (size_t)N * CH;
    uint2* sorted = (uint2*)(Qb + (size_t)N * CH);
    unsigned short* W = (unsigned short*)(sorted + ((E + 1) & ~1));
    unsigned int* meta = (unsigned int*)(W + 256 * KW);

    prep0<<<1, 64, 0, stream>>>(idxw, meta);
    hist_kern<<<512, 256, 0, stream>>>(idxw, E, M32, meta);
    scan_kern<<<1, 64, 0, stream>>>(meta, E);
    scatter_kern<<<1024, 256, 0, stream>>>(idxw, E, M32, meta, sorted);
    w1_prep<<<256, 192, 0, stream>>>(w1, b1, W);

    node_mfma3<<<(N + 31) / 32, 256, 0, stream>>>(tokens, coords, W, Pb, Qb, N);

    edge_sorted<<<4096, 256, 0, stream>>>(sorted, meta, (const char*)Pb,
                                          (const char*)Qb, w2, b2, out);
}

// Round 7
// 88.430 us; speedup vs baseline: 1.2034x; 1.2034x over previous
//
#include <hip/hip_runtime.h>

static constexpr int CH   = 128;   // CHANNELS
static constexpr int KW   = 160;   // W row length (bf16): 128 tok + wc0,wc1,b1 + pad
static constexpr int KPAD = 192;   // Atile row length (bf16) -> 384B rows

typedef __attribute__((ext_vector_type(8))) short bf16x8;
typedef __attribute__((ext_vector_type(4))) float f32x4;

__device__ inline unsigned short f2bf(float x) {
    unsigned int u = __float_as_uint(x);
    unsigned int r = (u + 0x7fffu + ((u >> 16) & 1u)) >> 16;  // RNE
    return (unsigned short)r;
}
__device__ inline unsigned int pack2bf(float a, float b) {
    return (unsigned int)f2bf(a) | ((unsigned int)f2bf(b) << 16);
}

// ---------------------------------------------------------------------------
// Detect whether edge_index arrived as int64 (JAX x64 on) or int32 (x64 off).
// ---------------------------------------------------------------------------
__global__ void detect_idx64(const unsigned int* __restrict__ idxw,
                             int* __restrict__ flag) {
    const int t = threadIdx.x;
    unsigned int nz = 0;
    for (int i = t; i < 128; i += 64) nz |= idxw[2 * i + 1];
    unsigned long long b = __ballot(nz != 0u);
    if (t == 0) flag[0] = (b == 0ULL) ? 1 : 0;
}

// ---------------------------------------------------------------------------
// idx2[e] = { src_byte_off, dst_byte_off } (row = 256B). Pads to Epad with 0.
// ---------------------------------------------------------------------------
__global__ __launch_bounds__(256) void idx_prep(
    const unsigned int* __restrict__ idxw, uint2* __restrict__ idx2,
    long long E, long long Epad, const int* __restrict__ flag) {
    const int is64 = flag[0];
    const long long stride = (long long)gridDim.x * blockDim.x;
    for (long long i = (long long)blockIdx.x * blockDim.x + threadIdx.x;
         i < Epad; i += stride) {
        uint2 v = make_uint2(0u, 0u);
        if (i < E) {
            const unsigned s = is64 ? idxw[2 * i] : idxw[i];
            const unsigned d = is64 ? idxw[2 * (E + i)] : idxw[E + i];
            v = make_uint2(s << 8, d << 8);
        }
        idx2[i] = v;
    }
}

// ---------------------------------------------------------------------------
// W[c][k] (bf16, [256][KW]): k<128 tok-weights; k=128/129 = +-wc0/wc1;
// k=130 = b1 (Q only); rest 0.
// ---------------------------------------------------------------------------
__global__ __launch_bounds__(192) void w1_prep(const float* __restrict__ w1,
                                               const float* __restrict__ b1,
                                               unsigned short* __restrict__ W) {
    const int c = blockIdx.x;    // 0..255
    const int k = threadIdx.x;
    if (k >= KW) return;
    const bool isQ = c >= 128;
    const int cc = c & 127;
    float v;
    if (k < 128)       v = isQ ? w1[(size_t)(128 + k) * CH + cc]
                               : w1[(size_t)k * CH + cc];
    else if (k == 128) v = (isQ ? 1.f : -1.f) * w1[(size_t)(2 * CH) * CH + cc];
    else if (k == 129) v = (isQ ? 1.f : -1.f) * w1[(size_t)(2 * CH + 1) * CH + cc];
    else if (k == 130) v = isQ ? b1[cc] : 0.f;
    else               v = 0.f;
    W[(size_t)c * KW + k] = f2bf(v);
}

// ---------------------------------------------------------------------------
// Node stage: 32 nodes x 256 cols per block. Swapped operands (A = W rows =
// output cols) -> packed 8B stores, no epilogue. Coords+bias folded via K=160.
// ---------------------------------------------------------------------------
__global__ __launch_bounds__(256) void node_mfma3(
    const float* __restrict__ tokens, const float* __restrict__ coords,
    const unsigned short* __restrict__ W, unsigned short* __restrict__ Pb,
    unsigned short* __restrict__ Qb, int N) {
    __shared__ unsigned short Atile[32 * KPAD];  // 12 KB, XOR-swizzled rows

    const int t    = threadIdx.x;
    const int l    = t & 63;
    const int wid  = t >> 6;
    const int n0   = blockIdx.x * 32;
    const int woff = wid * 64;
    const int bl   = l & 15;
    const int bh   = l >> 4;

    // token chunks: 32 nodes x 16 chunks of 16B
#pragma unroll
    for (int it = 0; it < 2; ++it) {
        const int idx  = it * 256 + t;
        const int node = idx >> 4;
        const int cq   = idx & 15;
        float4 v0 = make_float4(0.f, 0.f, 0.f, 0.f);
        float4 v1 = v0;
        if (n0 + node < N) {
            const float* src = &tokens[(size_t)(n0 + node) * CH + cq * 8];
            v0 = *(const float4*)src;
            v1 = *(const float4*)(src + 4);
        }
        uint4 u;
        u.x = pack2bf(v0.x, v0.y);
        u.y = pack2bf(v0.z, v0.w);
        u.z = pack2bf(v1.x, v1.y);
        u.w = pack2bf(v1.z, v1.w);
        const int byte = node * 384 + ((cq * 16) ^ ((node & 7) << 4));
        *(uint4*)((char*)Atile + byte) = u;
    }
    // ext chunks: k=128..191 -> (cx, cy, 1, 0, ...)
    {
        const int node = t >> 3;
        const int ce   = t & 7;
        uint4 u = make_uint4(0u, 0u, 0u, 0u);
        if (ce == 0 && n0 + node < N) {
            const float cx = coords[2 * (n0 + node)];
            const float cy = coords[2 * (n0 + node) + 1];
            u.x = pack2bf(cx, cy);
            u.y = pack2bf(1.f, 0.f);
        }
        const int byte = node * 384 + (((16 + ce) * 16) ^ ((node & 7) << 4));
        *(uint4*)((char*)Atile + byte) = u;
    }
    __syncthreads();

    f32x4 acc[4][2];
#pragma unroll
    for (int m = 0; m < 4; ++m)
#pragma unroll
        for (int n = 0; n < 2; ++n) acc[m][n] = (f32x4){0.f, 0.f, 0.f, 0.f};

#pragma unroll
    for (int ks = 0; ks < 5; ++ks) {
        bf16x8 wfrag[4], tfrag[2];
#pragma unroll
        for (int m = 0; m < 4; ++m)
            wfrag[m] = *(const bf16x8*)&W[(size_t)(woff + m * 16 + bl) * KW +
                                          ks * 32 + bh * 8];
#pragma unroll
        for (int n = 0; n < 2; ++n) {
            const int row  = n * 16 + bl;
            const int byte = row * 384 + ((ks * 64 + bh * 16) ^ ((row & 7) << 4));
            tfrag[n] = *(const bf16x8*)((const char*)Atile + byte);
        }
#pragma unroll
        for (int m = 0; m < 4; ++m)
#pragma unroll
            for (int n = 0; n < 2; ++n)
                acc[m][n] = __builtin_amdgcn_mfma_f32_16x16x32_bf16(
                    wfrag[m], tfrag[n], acc[m][n], 0, 0, 0);
    }

#pragma unroll
    for (int m = 0; m < 4; ++m) {
        const int c = woff + m * 16 + bh * 4;
        unsigned short* dst = (c < CH) ? Pb : Qb;
        const int cc = c & (CH - 1);
#pragma unroll
        for (int n = 0; n < 2; ++n) {
            const int node = n0 + n * 16 + bl;
            if (node < N) {
                uint2 val;
                val.x = pack2bf(acc[m][n][0], acc[m][n][1]);
                val.y = pack2bf(acc[m][n][2], acc[m][n][3]);
                *(uint2*)&dst[(size_t)node * CH + cc] = val;
            }
        }
    }
}

// ---------------------------------------------------------------------------
// Edge kernel: 16-lane group owns EIGHT edges/iter (16 outstanding gathers);
// lane covers 8 channels (16B).  out[e] = dot(relu(P[src]+Q[dst]), w2) + b2
// ---------------------------------------------------------------------------
__global__ __launch_bounds__(256) void edge_g16x8(
    const uint2* __restrict__ idx2, const char* __restrict__ Pb,
    const char* __restrict__ Qb, const float* __restrict__ w2,
    const float* __restrict__ b2, float* __restrict__ out, long long E) {
    const int t  = threadIdx.x;
    const int gl = t & 15;
    const long long nch = (E + 7) >> 3;  // 8-edge chunks
    const long long g0  = (long long)blockIdx.x * 16 + (t >> 4);
    const long long ng  = (long long)gridDim.x * 16;
    const float4 w2a = *(const float4*)&w2[8 * gl];
    const float4 w2b = *(const float4*)&w2[8 * gl + 4];
    const float bias = b2[0];

    for (long long chk = g0; chk < nch; chk += ng) {
        const long long e0 = chk << 3;
        const uint4* ip = (const uint4*)&idx2[e0];  // 64B, aligned
        const uint4 i0 = ip[0], i1 = ip[1], i2 = ip[2], i3 = ip[3];
        const unsigned soff[8] = {i0.x, i0.z, i1.x, i1.z, i2.x, i2.z, i3.x, i3.z};
        const unsigned doff[8] = {i0.y, i0.w, i1.y, i1.w, i2.y, i2.w, i3.y, i3.w};
        uint4 pv[8], qv[8];
#pragma unroll
        for (int j = 0; j < 8; ++j)
            pv[j] = *(const uint4*)(Pb + soff[j] + 16 * gl);
#pragma unroll
        for (int j = 0; j < 8; ++j)
            qv[j] = *(const uint4*)(Qb + doff[j] + 16 * gl);

        float part[8];
#pragma unroll
        for (int j = 0; j < 8; ++j) {
            float acc = 0.f;
            const unsigned pw[4] = {pv[j].x, pv[j].y, pv[j].z, pv[j].w};
            const unsigned qw[4] = {qv[j].x, qv[j].y, qv[j].z, qv[j].w};
            const float wv[8] = {w2a.x, w2a.y, w2a.z, w2a.w,
                                 w2b.x, w2b.y, w2b.z, w2b.w};
#pragma unroll
            for (int wdx = 0; wdx < 4; ++wdx) {
                const float plo = __uint_as_float(pw[wdx] << 16);
                const float phi = __uint_as_float(pw[wdx] & 0xffff0000u);
                const float qlo = __uint_as_float(qw[wdx] << 16);
                const float qhi = __uint_as_float(qw[wdx] & 0xffff0000u);
                const float hlo = fmaxf(plo + qlo, 0.f);
                const float hhi = fmaxf(phi + qhi, 0.f);
                acc = fmaf(hlo, wv[2 * wdx], acc);
                acc = fmaf(hhi, wv[2 * wdx + 1], acc);
            }
            part[j] = acc;
        }

        // butterfly with packing: lane (gl&7)=j ends holding edge j's sum
        float t0 = part[0] + __shfl_xor(part[0], 1);
        float t1 = part[1] + __shfl_xor(part[1], 1);
        float t2 = part[2] + __shfl_xor(part[2], 1);
        float t3 = part[3] + __shfl_xor(part[3], 1);
        float t4 = part[4] + __shfl_xor(part[4], 1);
        float t5 = part[5] + __shfl_xor(part[5], 1);
        float t6 = part[6] + __shfl_xor(part[6], 1);
        float t7 = part[7] + __shfl_xor(part[7], 1);
        float a0 = (gl & 1) ? t1 : t0;
        float a1 = (gl & 1) ? t3 : t2;
        float a2 = (gl & 1) ? t5 : t4;
        float a3 = (gl & 1) ? t7 : t6;
        a0 += __shfl_xor(a0, 2);
        a1 += __shfl_xor(a1, 2);
        a2 += __shfl_xor(a2, 2);
        a3 += __shfl_xor(a3, 2);
        float b0 = (gl & 2) ? a1 : a0;
        float b1v = (gl & 2) ? a3 : a2;
        b0  += __shfl_xor(b0, 4);
        b1v += __shfl_xor(b1v, 4);
        float c = (gl & 4) ? b1v : b0;
        c += __shfl_xor(c, 8);

        if (gl < 8 && e0 + gl < E) out[e0 + gl] = c + bias;
    }
}

extern "C" void kernel_launch(void* const* d_in, const int* in_sizes, int n_in,
                              void* d_out, int out_size, void* d_ws,
                              size_t ws_size, hipStream_t stream) {
    const float* tokens = (const float*)d_in[0];
    const float* coords = (const float*)d_in[1];
    const unsigned int* idxw = (const unsigned int*)d_in[2];
    const float* w1 = (const float*)d_in[3];
    const float* b1 = (const float*)d_in[4];
    const float* w2 = (const float*)d_in[5];
    const float* b2 = (const float*)d_in[6];
    float* out = (float*)d_out;

    const int N = in_sizes[0] / CH;       // 50000
    const long long E = in_sizes[2] / 2;  // 800000
    const long long Epad = ((E + 7) >> 3) << 3;

    unsigned short* Pb = (unsigned short*)d_ws;
    unsigned short* Qb = Pb + (size_t)N * CH;
    uint2* idx2 = (uint2*)(Qb + (size_t)N * CH);
    unsigned short* W = (unsigned short*)(idx2 + Epad);
    int* flag = (int*)(W + 256 * KW);

    detect_idx64<<<1, 64, 0, stream>>>(idxw, flag);
    idx_prep<<<1024, 256, 0, stream>>>(idxw, idx2, E, Epad, flag);
    w1_prep<<<256, 192, 0, stream>>>(w1, b1, W);

    node_mfma3<<<(N + 31) / 32, 256, 0, stream>>>(tokens, coords, W, Pb, Qb, N);

    edge_g16x8<<<2048, 256, 0, stream>>>(idx2, (const char*)Pb, (const char*)Qb,
                                         w2, b2, out, E);
}